// Round 7
// baseline (1117.011 us; speedup 1.0000x reference)
//
#include <hip/hip_runtime.h>
#include <hip/hip_bf16.h>
#include <cstdint>

#define LH   50
#define PP   30
#define NAG  2048
#define NHID 128
#define EHID 256
#define ADIM 64
#define CNND 2048

typedef __attribute__((ext_vector_type(8))) short bf16x8;
typedef __attribute__((ext_vector_type(4))) float f32x4;

// ---- workspace layout (float slots) -----------------------------------------
enum : int {
  WS_WT  = 0,         // bf16 chunks c=0..3 [4][1024][32]      -> 65536 fl (256KB)
  WS_WC  = 65536,     // bf16 stream image x16 copies [16][4][1024][32] -> 1048576 fl (4MB)
  WS_WHT = 1114112,   // bf16 WhtT[512][128] -> 32768
  WS_WFN = 1146880,   // 2*1024 folded (W_nemb@Wih_n)
  WS_BFN = 1148928,   // 1024
  WS_WFT = 1149952,   // 2*512 folded (W_temb@Wih_t)
  WS_BFT = 1150976,   // 512
  WS_TH  = 1151488,   // 128
  WS_TC  = 1151616,   // 128
  WS_W49 = 1151744,   // 2048
  WS_CN  = 1153792,   // 1 (+3 pad)
  WS_Z   = 1153796,   // 30*2048*2
  WS_END = 1276676
};

__device__ __forceinline__ float sigf(float x){ return 1.0f/(1.0f + __expf(-x)); }
__device__ __forceinline__ float tanhfast(float x){
  x = fminf(15.0f, fmaxf(-15.0f, x));
  float e = __expf(2.0f*x);
  return (e - 1.0f)/(e + 1.0f);
}
__device__ __forceinline__ float bfs(short s){
  return __uint_as_float(((unsigned)(unsigned short)s) << 16);
}

// ---- prep --------------------------------------------------------------------
// b<128: chunks 0..3 -> WS_WT; b in [128,256): chunks 4..7 -> WS_WC copy 0;
// b==256: folds + WhtT.
__global__ void k_prep(const float* __restrict__ Whhn, const float* __restrict__ Whht,
                       const float* __restrict__ Wnemb, const float* __restrict__ bnemb,
                       const float* __restrict__ Wihn,  const float* __restrict__ bihn,
                       const float* __restrict__ bhhn,
                       const float* __restrict__ Wtemb, const float* __restrict__ btemb,
                       const float* __restrict__ Wiht,  const float* __restrict__ biht,
                       const float* __restrict__ bhht,
                       float* __restrict__ ws)
{
  const int b = blockIdx.x, tid = threadIdx.x;
  if (b < 256){
    __shared__ float t[32][33];
    const int tx = tid & 31, ty = tid >> 5;     // ty in [0,8)
    const int j0 = (b & 31) << 5;
    const int e0 = (b >> 5) << 5;               // [0,256)
    #pragma unroll
    for (int r = 0; r < 4; ++r)
      t[ty + 8*r][tx] = Whhn[(e0 + ty + 8*r)*1024 + j0 + tx];
    __syncthreads();
    const int c = e0 >> 5;                      // 0..7
    __hip_bfloat16* dst = (c < 4)
        ? (__hip_bfloat16*)(ws + WS_WT) + c*32768
        : (__hip_bfloat16*)(ws + WS_WC) + (c-4)*32768;
    #pragma unroll
    for (int r = 0; r < 4; ++r)
      dst[(j0 + ty + 8*r)*32 + tx] = __float2bfloat16(t[tx][ty + 8*r]);
  } else {
    for (int j = tid; j < 1024; j += 256){
      float a0=0.f, a1=0.f, ab=0.f;
      for (int k=0;k<64;k++){
        const float w = Wihn[k*1024 + j];
        a0 += Wnemb[k]*w; a1 += Wnemb[64+k]*w; ab += bnemb[k]*w;
      }
      ws[WS_WFN + j]        = a0;
      ws[WS_WFN + 1024 + j] = a1;
      ws[WS_BFN + j]        = ab + bihn[j] + bhhn[j];
    }
    for (int j = tid; j < 512; j += 256){
      float a0=0.f, a1=0.f, ab=0.f;
      for (int k=0;k<64;k++){
        const float w = Wiht[k*512 + j];
        a0 += Wtemb[k]*w; a1 += Wtemb[64+k]*w; ab += btemb[k]*w;
      }
      ws[WS_WFT + j]       = a0;
      ws[WS_WFT + 512 + j] = a1;
      ws[WS_BFT + j]       = ab + biht[j] + bhht[j];
    }
    __hip_bfloat16* WTt = (__hip_bfloat16*)(ws + WS_WHT);
    for (int j = tid; j < 512; j += 256)
      for (int k = 0; k < 128; ++k)
        WTt[j*128 + k] = __float2bfloat16(Whht[k*512 + j]);
  }
}

// ---- duplicate stream image into copies 1..15 --------------------------------
__global__ void k_dup(float* __restrict__ ws)
{
  const int i = blockIdx.x*256 + threadIdx.x;   // 960*256 = 245760 = 15*16384
  const int m  = 1 + (i >> 14);
  const int si = (i & 16383)*4;
  *(float4*)(ws + WS_WC + m*65536 + si) = *(const float4*)(ws + WS_WC + si);
}

// ---- Phase A ------------------------------------------------------------------
// b<128: 16-agent 78-step nearby chain. k[0,128) in VGPR (wreg);
//        k[128,256) streamed global->VGPR (2-deep ring, 16 copies, rotated order).
// b==128: target obs chain.  b==129: w49 precompute.
__global__ __launch_bounds__(512, 2) void k_phaseA(
    const float* __restrict__ nh0, const float* __restrict__ nc0,
    const float* __restrict__ nrel, const int* __restrict__ nhist,
    const float* __restrict__ Wpred,
    const float* __restrict__ trel, const int* __restrict__ thsp,
    const float* __restrict__ Whht, const float* __restrict__ th0,
    const float* __restrict__ tc0,
    const float* __restrict__ tpos, const float* __restrict__ npos,
    const float* __restrict__ Wtatt, const float* __restrict__ btatt,
    const float* __restrict__ Wnatt, const float* __restrict__ bnatt,
    float* __restrict__ ws)
{
  __shared__ short Hl[16*264];
  __shared__ float relS[1600];
  __shared__ float vS[512];
  __shared__ float wfS[3072];
  const int b = blockIdx.x, tid = threadIdx.x;
  const int wv = tid >> 6, lane = tid & 63;
  const int lhi = lane >> 4, llo = lane & 15;

  if (b < 128){
    const int n0  = b << 4;
    const int rot = (b >> 4) & 3;
    const int cid = (b & 7)*2 + ((b >> 3) & 1);
    const short* wst = (const short*)(ws + WS_WC) + cid*131072;
    const int jcol = (wv << 5) + llo;

    // one-time: register-resident half (k in [0,128))
    bf16x8 wreg[4][2][4];
    {
      const short* wt = (const short*)(ws + WS_WT);
      #pragma unroll
      for (int g = 0; g < 4; ++g)
        #pragma unroll
        for (int t = 0; t < 2; ++t){
          const int j = g*256 + jcol + t*16;
          #pragma unroll
          for (int ks = 0; ks < 4; ++ks)
            wreg[g][t][ks] = *(const bf16x8*)(wt + ks*32768 + j*32 + lhi*8);
        }
    }
    // prologue stream prefetch: chunks cs(0), cs(1)
    bf16x8 s0[8], s1[8];
    {
      const int cA = (rot) & 3, cB = (1 + rot) & 3;
      #pragma unroll
      for (int g = 0; g < 4; ++g)
        #pragma unroll
        for (int t = 0; t < 2; ++t){
          const int j = g*256 + jcol + t*16;
          s0[g*2+t] = *(const bf16x8*)(wst + cA*32768 + j*32 + lhi*8);
          s1[g*2+t] = *(const bf16x8*)(wst + cB*32768 + j*32 + lhi*8);
        }
    }
    // shared init
    for (int i = tid; i < 1600; i += 512){
      const int a = i / 100, r = i % 100;
      relS[a*100 + r] = nrel[(n0 + a)*100 + r];
    }
    if (tid < 256){
      vS[2*tid]   = Wpred[2*(NHID + CNND + tid)];
      vS[2*tid+1] = Wpred[2*(NHID + CNND + tid) + 1];
    }
    for (int i = tid; i < 1024; i += 512){
      wfS[i]        = ws[WS_WFN + i];
      wfS[1024 + i] = ws[WS_WFN + 1024 + i];
      wfS[2048 + i] = ws[WS_BFN + i];
    }
    for (int i = tid; i < 4096; i += 512){
      const int a = i >> 8, e = i & 255;
      ((__hip_bfloat16*)Hl)[a*264 + e] = __float2bfloat16(nh0[e]);
    }
    float C[4][2];
    #pragma unroll
    for (int r = 0; r < 4; ++r)
      #pragma unroll
      for (int t = 0; t < 2; ++t)
        C[r][t] = nc0[jcol + t*16];
    int nh4[4];
    #pragma unroll
    for (int r = 0; r < 4; ++r) nh4[r] = nhist[n0 + lhi*4 + r];

    __syncthreads();

    for (int st = 1; st <= 78; ++st){
      const int thr  = (st <= 49) ? (50 - st) : -1;
      const int tsel = (st <= 49) ? st : 49;

      f32x4 acc[4][2];
      #pragma unroll
      for (int g = 0; g < 4; ++g)
        #pragma unroll
        for (int t = 0; t < 2; ++t) acc[g][t] = (f32x4){0.f,0.f,0.f,0.f};

      // register half
      #pragma unroll
      for (int ks = 0; ks < 4; ++ks){
        const bf16x8 afr = *(const bf16x8*)(Hl + llo*264 + ks*32 + lhi*8);
        #pragma unroll
        for (int g = 0; g < 4; ++g)
          #pragma unroll
          for (int t = 0; t < 2; ++t)
            acc[g][t] = __builtin_amdgcn_mfma_f32_16x16x32_bf16(afr, wreg[g][t][ks], acc[g][t], 0,0,0);
      }
      // streamed half: consume ring slot, refill with chunk i+2
      #pragma unroll
      for (int i = 0; i < 4; ++i){
        const int cs  = 4 + ((i + rot) & 3);
        const int c2o = ((i + 2 + rot) & 3)*32768;
        const bf16x8 afs = *(const bf16x8*)(Hl + llo*264 + cs*32 + lhi*8);
        if ((i & 1) == 0){
          #pragma unroll
          for (int g = 0; g < 4; ++g)
            #pragma unroll
            for (int t = 0; t < 2; ++t)
              acc[g][t] = __builtin_amdgcn_mfma_f32_16x16x32_bf16(afs, s0[g*2+t], acc[g][t], 0,0,0);
          #pragma unroll
          for (int g = 0; g < 4; ++g)
            #pragma unroll
            for (int t = 0; t < 2; ++t)
              s0[g*2+t] = *(const bf16x8*)(wst + c2o + (g*256 + jcol + t*16)*32 + lhi*8);
        } else {
          #pragma unroll
          for (int g = 0; g < 4; ++g)
            #pragma unroll
            for (int t = 0; t < 2; ++t)
              acc[g][t] = __builtin_amdgcn_mfma_f32_16x16x32_bf16(afs, s1[g*2+t], acc[g][t], 0,0,0);
          #pragma unroll
          for (int g = 0; g < 4; ++g)
            #pragma unroll
            for (int t = 0; t < 2; ++t)
              s1[g*2+t] = *(const bf16x8*)(wst + c2o + (g*256 + jcol + t*16)*32 + lhi*8);
        }
      }

      // barrier 1: all waves' Hl reads of this step complete
      asm volatile("s_waitcnt lgkmcnt(0)" ::: "memory");
      __builtin_amdgcn_sched_barrier(0);
      __builtin_amdgcn_s_barrier();
      __builtin_amdgcn_sched_barrier(0);

      // gates + masked in-place H update
      {
        float wfa[4][2], wfb[4][2], wbb[4][2];
        #pragma unroll
        for (int g = 0; g < 4; ++g)
          #pragma unroll
          for (int t = 0; t < 2; ++t){
            const int j = g*256 + jcol + t*16;
            wfa[g][t] = wfS[j]; wfb[g][t] = wfS[1024 + j]; wbb[g][t] = wfS[2048 + j];
          }
        #pragma unroll
        for (int r = 0; r < 4; ++r){
          const int ag = lhi*4 + r;
          const float r0 = relS[ag*100 + 2*tsel];
          const float r1 = relS[ag*100 + 2*tsel + 1];
          const bool mk = nh4[r] > thr;
          #pragma unroll
          for (int t = 0; t < 2; ++t){
            const float gi = acc[0][t][r] + r0*wfa[0][t] + r1*wfb[0][t] + wbb[0][t];
            const float gf = acc[1][t][r] + r0*wfa[1][t] + r1*wfb[1][t] + wbb[1][t];
            const float gg = acc[2][t][r] + r0*wfa[2][t] + r1*wfb[2][t] + wbb[2][t];
            const float go = acc[3][t][r] + r0*wfa[3][t] + r1*wfb[3][t] + wbb[3][t];
            const float c2 = sigf(gf)*C[r][t] + sigf(gi)*tanhfast(gg);
            const float h2 = sigf(go)*tanhfast(c2);
            if (mk){
              C[r][t] = c2;
              ((__hip_bfloat16*)Hl)[ag*264 + jcol + t*16] = __float2bfloat16(h2);
            }
          }
        }
      }
      // barrier 2: H updates visible block-wide
      asm volatile("s_waitcnt lgkmcnt(0)" ::: "memory");
      __builtin_amdgcn_sched_barrier(0);
      __builtin_amdgcn_s_barrier();
      __builtin_amdgcn_sched_barrier(0);

      if (st >= 49){
        const int s = st - 49;
        const int a = wv*2 + (lane >> 5);
        const int sub = lane & 31;
        float z0 = 0.f, z1 = 0.f;
        const short* hp = Hl + a*264 + sub*8;
        #pragma unroll
        for (int i = 0; i < 8; ++i){
          const float h = bfs(hp[i]);
          z0 += h*vS[2*(sub*8 + i)];
          z1 += h*vS[2*(sub*8 + i) + 1];
        }
        #pragma unroll
        for (int o = 16; o > 0; o >>= 1){
          z0 += __shfl_down(z0, o, 32);
          z1 += __shfl_down(z1, o, 32);
        }
        if (sub == 0){
          ws[WS_Z + (s*NAG + n0 + a)*2]     = z0;
          ws[WS_Z + (s*NAG + n0 + a)*2 + 1] = z1;
        }
      }
    }
  }
  else if (b == 128){
    float* hT = relS;
    float* cT = relS + 128;
    float* gT = relS + 256;   // 512
    if (tid < 128){ hT[tid] = th0[tid]; cT[tid] = tc0[tid]; }
    __syncthreads();
    const int ths = thsp[0];
    for (int t = 1; t < 50; ++t){
      const float x0 = trel[2*t], x1 = trel[2*t+1];
      float acc = x0*ws[WS_WFT + tid] + x1*ws[WS_WFT + 512 + tid] + ws[WS_BFT + tid];
      for (int k = 0; k < 128; ++k) acc += hT[k]*Whht[k*512 + tid];
      gT[tid] = acc;
      __syncthreads();
      if (tid < 128 && ths > 50 - t){
        const float ig = sigf(gT[tid]),          fg = sigf(gT[128 + tid]);
        const float gg = tanhfast(gT[256 + tid]), og = sigf(gT[384 + tid]);
        const float c2 = fg*cT[tid] + ig*gg;
        cT[tid] = c2; hT[tid] = og*tanhfast(c2);
      }
      __syncthreads();
    }
    if (tid < 128){ ws[WS_TH + tid] = hT[tid]; ws[WS_TC + tid] = cT[tid]; }
  }
  else {
    float* at  = vS;          // 64
    float* red = relS;        // 512
    float* uv  = vS + 64;     // 3
    const int t = LH - 1;
    const float tr0 = trel[2*t], tr1 = trel[2*t+1];
    const float tp0 = tpos[2*t], tp1 = tpos[2*t+1];
    if (tid < ADIM) at[tid] = tr0*Wtatt[tid] + tr1*Wtatt[ADIM+tid] + btatt[tid];
    int cnt = 0;
    #pragma unroll
    for (int i = 0; i < 4; ++i) cnt += (nhist[tid + 512*i] > (LH - t)) ? 1 : 0;
    red[tid] = (float)cnt;
    __syncthreads();
    if (tid == 0){
      float u0=0.f,u1=0.f,v=0.f;
      for (int k=0;k<ADIM;k++){ u0 += Wnatt[k]*at[k]; u1 += Wnatt[ADIM+k]*at[k]; v += bnatt[k]*at[k]; }
      uv[0]=u0; uv[1]=u1; uv[2]=v;
    }
    for (int s = 256; s > 0; s >>= 1){ if (tid < s) red[tid] += red[tid+s]; __syncthreads(); }
    const float currN = red[0];
    __syncthreads();
    const float u0 = uv[0], u1 = uv[1], v = uv[2];
    const float scale = currN * 0.125f;
    float sc[4]; float smax = -3.0e38f;
    #pragma unroll
    for (int i = 0; i < 4; ++i){
      const int n = tid + 512*i;
      const float p0 = npos[n*100 + 2*t], p1 = npos[n*100 + 2*t + 1];
      float s = scale * ((tp0-p0)*u0 + (tp1-p1)*u1 + v);
      s = (nhist[n] > (LH - t)) ? s : -1.0e30f;
      sc[i] = s; smax = fmaxf(smax, s);
    }
    red[tid] = smax; __syncthreads();
    for (int s = 256; s > 0; s >>= 1){ if (tid<s) red[tid] = fmaxf(red[tid], red[tid+s]); __syncthreads(); }
    smax = red[0]; __syncthreads();
    float ssum = 0.f;
    #pragma unroll
    for (int i = 0; i < 4; ++i){ sc[i] = __expf(sc[i]-smax); ssum += sc[i]; }
    red[tid] = ssum; __syncthreads();
    for (int s = 256; s > 0; s >>= 1){ if (tid<s) red[tid] += red[tid+s]; __syncthreads(); }
    const float inv = 1.0f / red[0];
    #pragma unroll
    for (int i = 0; i < 4; ++i) ws[WS_W49 + tid + 512*i] = sc[i]*inv;
    if (tid == 0) ws[WS_CN] = currN;
  }
}

// ---- Phase B: all 30 pred steps in one block ---------------------------------
template<int K>
__device__ __forceinline__ void bredN(const float* v, volatile float* scratch,
                                      volatile float* outv, int tid){
  const int lane = tid & 63, wv = tid >> 6;
  #pragma unroll
  for (int k = 0; k < K; ++k){
    float x = v[k];
    #pragma unroll
    for (int o = 32; o > 0; o >>= 1) x += __shfl_down(x, o, 64);
    if (lane == 0) scratch[k*8 + wv] = x;
  }
  __syncthreads();
  if (tid == 0){
    #pragma unroll
    for (int k = 0; k < K; ++k){
      float s = 0.f;
      for (int i = 0; i < 8; ++i) s += scratch[k*8 + i];
      outv[k] = s;
    }
  }
  __syncthreads();
}

__device__ __forceinline__ float bredMax1(float x, volatile float* scratch,
                                          volatile float* outv, int tid){
  const int lane = tid & 63, wv = tid >> 6;
  #pragma unroll
  for (int o = 32; o > 0; o >>= 1) x = fmaxf(x, __shfl_down(x, o, 64));
  if (lane == 0) scratch[wv] = x;
  __syncthreads();
  if (tid == 0){
    float s = -3.0e38f;
    for (int i = 0; i < 8; ++i) s = fmaxf(s, scratch[i]);
    outv[0] = s;
  }
  __syncthreads();
  return outv[0];
}

__global__ __launch_bounds__(512, 1) void k_phaseB(
    const float* __restrict__ img, const float* __restrict__ tpos,
    const float* __restrict__ npos, const float* __restrict__ nh0,
    const float* __restrict__ Wpred, const float* __restrict__ bpred,
    const float* __restrict__ Wtatt, const float* __restrict__ btatt,
    const float* __restrict__ Wnatt, const float* __restrict__ bnatt,
    float* __restrict__ ws, float* __restrict__ out)
{
  __shared__ float p0s[NAG], p1s[NAG];
  __shared__ float th[128], tc[128], gl[512], at[64];
  __shared__ float scratch[24];
  __shared__ float bc[8];
  const int tid = threadIdx.x, lane = tid & 63, wv = tid >> 6;

  bf16x8 wreg[16];
  {
    const short* wp = (const short*)(ws + WS_WHT) + tid*128;
    #pragma unroll
    for (int f = 0; f < 16; ++f) wreg[f] = *(const bf16x8*)(wp + f*8);
  }
  for (int n = tid; n < NAG; n += 512){
    p0s[n] = npos[n*100 + 98];
    p1s[n] = npos[n*100 + 99];
  }
  if (tid < 128){ th[tid] = ws[WS_TH + tid]; tc[tid] = ws[WS_TC + tid]; }

  {
    float v[2] = {0.f, 0.f};
    for (int k = tid; k < CNND; k += 512){
      v[0] += img[k]*Wpred[2*(128 + k)];
      v[1] += img[k]*Wpred[2*(128 + k) + 1];
    }
    bredN<2>(v, scratch, bc, tid);
  }
  const float imgW0 = bc[0], imgW1 = bc[1];
  {
    float v[2] = {0.f, 0.f};
    if (tid < 256){
      v[0] = nh0[tid]*Wpred[2*(128 + CNND + tid)];
      v[1] = nh0[tid]*Wpred[2*(128 + CNND + tid) + 1];
    }
    bredN<2>(v, scratch, bc + 2, tid);
  }
  const float fb0 = bc[2], fb1 = bc[3];
  const float currN = ws[WS_CN];
  float pos0 = tpos[98], pos1 = tpos[99];
  float u0 = 0.f, u1 = 0.f, A = 0.f;
  __syncthreads();

  for (int s = 0; s < PP; ++s){
    const float* zs = ws + WS_Z + s*(NAG*2);
    float hv0, hv1;
    if (s == 0){
      if (currN >= 1.0f){
        float v[2] = {0.f, 0.f};
        for (int n = tid; n < NAG; n += 512){
          const float w = ws[WS_W49 + n];
          v[0] += w*zs[2*n]; v[1] += w*zs[2*n + 1];
        }
        bredN<2>(v, scratch, bc, tid);
        hv0 = bc[0]; hv1 = bc[1];
      } else { hv0 = fb0; hv1 = fb1; }
    } else {
      float sc[4], mx = -3.0e38f;
      #pragma unroll
      for (int i = 0; i < 4; ++i){
        const int n = tid + 512*i;
        sc[i] = 256.0f * (A - (p0s[n]*u0 + p1s[n]*u1));
        mx = fmaxf(mx, sc[i]);
      }
      mx = bredMax1(mx, scratch, bc + 7, tid);
      float v[3] = {0.f, 0.f, 0.f};
      #pragma unroll
      for (int i = 0; i < 4; ++i){
        const int n = tid + 512*i;
        const float e = __expf(sc[i] - mx);
        v[0] += e; v[1] += e*zs[2*n]; v[2] += e*zs[2*n + 1];
      }
      bredN<3>(v, scratch, bc, tid);
      const float inv = 1.0f / bc[0];
      hv0 = bc[1]*inv; hv1 = bc[2]*inv;
    }
    {
      float v[2] = {0.f, 0.f};
      if (tid < 128){
        v[0] = th[tid]*Wpred[2*tid];
        v[1] = th[tid]*Wpred[2*tid + 1];
      }
      bredN<2>(v, scratch, bc + 2, tid);
    }
    const float pr0 = bc[2] + imgW0 + hv0 + bpred[0];
    const float pr1 = bc[3] + imgW1 + hv1 + bpred[1];
    if (tid == 0){ out[2*s] = pr0; out[2*s + 1] = pr1; }
    pos0 += pr0; pos1 += pr1;

    {
      float g = pr0*ws[WS_WFT + tid] + pr1*ws[WS_WFT + 512 + tid] + ws[WS_BFT + tid];
      #pragma unroll
      for (int f = 0; f < 16; ++f){
        #pragma unroll
        for (int i = 0; i < 8; ++i)
          g += bfs(wreg[f][i]) * th[f*8 + i];
      }
      gl[tid] = g;
    }
    __syncthreads();
    float hnew = 0.f, cnew = 0.f;
    if (tid < 128){
      const float ig = sigf(gl[tid]),           fg = sigf(gl[128 + tid]);
      const float gg = tanhfast(gl[256 + tid]), og = sigf(gl[384 + tid]);
      cnew = fg*tc[tid] + ig*gg;
      hnew = og*tanhfast(cnew);
    }
    __syncthreads();
    if (tid < 128){ th[tid] = hnew; tc[tid] = cnew; }

    if (tid < ADIM) at[tid] = pr0*Wtatt[tid] + pr1*Wtatt[ADIM + tid] + btatt[tid];
    __syncthreads();
    if (wv == 0){
      float uu0 = Wnatt[lane]*at[lane];
      float uu1 = Wnatt[ADIM + lane]*at[lane];
      float vv  = bnatt[lane]*at[lane];
      #pragma unroll
      for (int o = 32; o > 0; o >>= 1){
        uu0 += __shfl_down(uu0, o, 64);
        uu1 += __shfl_down(uu1, o, 64);
        vv  += __shfl_down(vv,  o, 64);
      }
      if (lane == 0){
        bc[4] = uu0; bc[5] = uu1;
        bc[6] = pos0*uu0 + pos1*uu1 + vv;
      }
    }
    __syncthreads();
    u0 = bc[4]; u1 = bc[5]; A = bc[6];
  }
}

extern "C" void kernel_launch(void* const* d_in, const int* in_sizes, int n_in,
                              void* d_out, int out_size, void* d_ws, size_t ws_size,
                              hipStream_t stream) {
  const float* img   = (const float*)d_in[0];
  const float* tpos  = (const float*)d_in[1];
  const float* trel  = (const float*)d_in[2];
  const float* npos  = (const float*)d_in[3];
  const float* nrel  = (const float*)d_in[4];
  const int*   nhist = (const int*)d_in[5];
  const int*   ths   = (const int*)d_in[6];
  const float* th0   = (const float*)d_in[7];
  const float* tc0   = (const float*)d_in[8];
  const float* Wtemb = (const float*)d_in[9];
  const float* btemb = (const float*)d_in[10];
  const float* Wiht  = (const float*)d_in[11];
  const float* Whht  = (const float*)d_in[12];
  const float* biht  = (const float*)d_in[13];
  const float* bhht  = (const float*)d_in[14];
  const float* Wtatt = (const float*)d_in[15];
  const float* btatt = (const float*)d_in[16];
  const float* nh0   = (const float*)d_in[17];
  const float* nc0   = (const float*)d_in[18];
  const float* Wnemb = (const float*)d_in[19];
  const float* bnemb = (const float*)d_in[20];
  const float* Wihn  = (const float*)d_in[21];
  const float* Whhn  = (const float*)d_in[22];
  const float* bihn  = (const float*)d_in[23];
  const float* bhhn  = (const float*)d_in[24];
  const float* Wnatt = (const float*)d_in[25];
  const float* bnatt = (const float*)d_in[26];
  const float* Wpred = (const float*)d_in[27];
  const float* bpred = (const float*)d_in[28];
  float* ws  = (float*)d_ws;
  float* out = (float*)d_out;

  k_prep<<<257, 256, 0, stream>>>(Whhn, Whht, Wnemb, bnemb, Wihn, bihn, bhhn,
                                  Wtemb, btemb, Wiht, biht, bhht, ws);
  k_dup<<<960, 256, 0, stream>>>(ws);
  k_phaseA<<<130, 512, 0, stream>>>(nh0, nc0, nrel, nhist, Wpred,
                                    trel, ths, Whht, th0, tc0,
                                    tpos, npos, Wtatt, btatt, Wnatt, bnatt, ws);
  k_phaseB<<<1, 512, 0, stream>>>(img, tpos, npos, nh0, Wpred, bpred,
                                  Wtatt, btatt, Wnatt, bnatt, ws, out);
}

// Round 8
// 977.440 us; speedup vs baseline: 1.1428x; 1.1428x over previous
//
#include <hip/hip_runtime.h>
#include <hip/hip_bf16.h>
#include <cstdint>

#define LH   50
#define PP   30
#define NAG  2048
#define NHID 128
#define EHID 256
#define ADIM 64
#define CNND 2048

typedef __attribute__((ext_vector_type(8))) short bf16x8;
typedef __attribute__((ext_vector_type(4))) float f32x4;

// ---- workspace layout (float slots) -----------------------------------------
enum : int {
  WS_WT  = 0,        // bf16 chunks [8][1024][32] (k-chunked WhhT) -> 131072 fl (512KB)
  WS_WHT = 131072,   // bf16 WhtT[512][128] -> 32768
  WS_WFN = 163840,   // wf0[1024] wf1[1024] (folded W_nemb@Wih_n)
  WS_BFN = 165888,   // wb[1024]
  WS_WFT = 166912,   // 2*512 folded (W_temb@Wih_t)
  WS_BFT = 167936,   // 512
  WS_TH  = 168448,   // 128
  WS_TC  = 168576,   // 128
  WS_W49 = 168704,   // 2048
  WS_CN  = 170752,   // 1 (+3 pad)
  WS_Z   = 170756,   // 30*2048*2
  WS_END = 293636
};

#define HLH 4224   // shorts per Hl buffer (16 rows x 264)

__device__ __forceinline__ float sigf(float x){ return 1.0f/(1.0f + __expf(-x)); }
__device__ __forceinline__ float tanhfast(float x){
  x = fminf(15.0f, fmaxf(-15.0f, x));
  float e = __expf(2.0f*x);
  return (e - 1.0f)/(e + 1.0f);
}
__device__ __forceinline__ float bfs(short s){
  return __uint_as_float(((unsigned)(unsigned short)s) << 16);
}

// ---- prep: WhhT k-chunks [8][1024][32], WhtT, folded gate weights ------------
__global__ void k_prep(const float* __restrict__ Whhn, const float* __restrict__ Whht,
                       const float* __restrict__ Wnemb, const float* __restrict__ bnemb,
                       const float* __restrict__ Wihn,  const float* __restrict__ bihn,
                       const float* __restrict__ bhhn,
                       const float* __restrict__ Wtemb, const float* __restrict__ btemb,
                       const float* __restrict__ Wiht,  const float* __restrict__ biht,
                       const float* __restrict__ bhht,
                       float* __restrict__ ws)
{
  const int b = blockIdx.x, tid = threadIdx.x;
  if (b < 256){
    __shared__ float t[32][33];
    __hip_bfloat16* WT = (__hip_bfloat16*)(ws + WS_WT);
    const int tx = tid & 31, ty = tid >> 5;     // ty in [0,8)
    const int j0 = (b & 31) << 5;
    const int e0 = (b >> 5) << 5;               // k-range [0,256)
    #pragma unroll
    for (int r = 0; r < 4; ++r)
      t[ty + 8*r][tx] = Whhn[(e0 + ty + 8*r)*1024 + j0 + tx];
    __syncthreads();
    const int c = e0 >> 5;                      // 0..7
    #pragma unroll
    for (int r = 0; r < 4; ++r)
      WT[c*32768 + (j0 + ty + 8*r)*32 + tx] = __float2bfloat16(t[tx][ty + 8*r]);
  } else {
    for (int j = tid; j < 1024; j += 256){
      float a0=0.f, a1=0.f, ab=0.f;
      for (int k=0;k<64;k++){
        const float w = Wihn[k*1024 + j];
        a0 += Wnemb[k]*w; a1 += Wnemb[64+k]*w; ab += bnemb[k]*w;
      }
      ws[WS_WFN + j]        = a0;
      ws[WS_WFN + 1024 + j] = a1;
      ws[WS_BFN + j]        = ab + bihn[j] + bhhn[j];
    }
    for (int j = tid; j < 512; j += 256){
      float a0=0.f, a1=0.f, ab=0.f;
      for (int k=0;k<64;k++){
        const float w = Wiht[k*512 + j];
        a0 += Wtemb[k]*w; a1 += Wtemb[64+k]*w; ab += btemb[k]*w;
      }
      ws[WS_WFT + j]       = a0;
      ws[WS_WFT + 512 + j] = a1;
      ws[WS_BFT + j]       = ab + biht[j] + bhht[j];
    }
    __hip_bfloat16* WTt = (__hip_bfloat16*)(ws + WS_WHT);
    for (int j = tid; j < 512; j += 256)
      for (int k = 0; k < 128; ++k)
        WTt[j*128 + k] = __float2bfloat16(Whht[k*512 + j]);
  }
}

// ---- Phase A ------------------------------------------------------------------
// b<128: 16-agent 78-step nearby chain. FULL W on-CU:
//   k[0,128) in wreg (128 VGPR), k[128,192) in LDS (128KB, staged once),
//   k[192,256) in s67 (64 VGPR). Zero weight streaming in the loop.
//   H double-buffered in LDS -> ONE barrier per step.
// b==128: target obs chain.  b==129: w49 precompute.
// dynamic LDS: wlds 131072 | Hl 2x4224 shorts (16896) | wfS 3072 fl | vS 512 fl
__global__ __launch_bounds__(512, 1) void k_phaseA(
    const float* __restrict__ nh0, const float* __restrict__ nc0,
    const float* __restrict__ nrel, const int* __restrict__ nhist,
    const float* __restrict__ Wpred,
    const float* __restrict__ trel, const int* __restrict__ thsp,
    const float* __restrict__ Whht, const float* __restrict__ th0,
    const float* __restrict__ tc0,
    const float* __restrict__ tpos, const float* __restrict__ npos,
    const float* __restrict__ Wtatt, const float* __restrict__ btatt,
    const float* __restrict__ Wnatt, const float* __restrict__ bnatt,
    float* __restrict__ ws)
{
  extern __shared__ char smem[];
  const int b = blockIdx.x, tid = threadIdx.x;
  const int wv = tid >> 6, lane = tid & 63;
  const int lhi = lane >> 4, llo = lane & 15;

  if (b < 128){
    short* wlds = (short*)smem;                   // [2][1024][32] shorts (131072 B)
    short* Hl   = (short*)(smem + 131072);        // 2 x 4224 shorts
    float* wfS  = (float*)(smem + 147968);        // 3072 floats
    float* vS   = (float*)(smem + 160256);        // 512 floats
    const int n0 = b << 4;
    const int jcol = (wv << 5) + llo;
    const short* wt = (const short*)(ws + WS_WT);

    // register-resident W: k[0,128) and k[192,256)
    bf16x8 wreg[4][2][4];
    bf16x8 s67[4][2][2];
    #pragma unroll
    for (int g = 0; g < 4; ++g)
      #pragma unroll
      for (int t = 0; t < 2; ++t){
        const int j = g*256 + jcol + t*16;
        #pragma unroll
        for (int ks = 0; ks < 4; ++ks)
          wreg[g][t][ks] = *(const bf16x8*)(wt + ks*32768 + j*32 + lhi*8);
        #pragma unroll
        for (int i = 0; i < 2; ++i)
          s67[g][t][i] = *(const bf16x8*)(wt + (6+i)*32768 + j*32 + lhi*8);
      }
    // LDS-resident W: chunks 4,5 (linear copy, staged once)
    for (int i = tid; i < 8192; i += 512)
      *(uint4*)(wlds + i*8) = *(const uint4*)(wt + 4*32768 + i*8);
    // gate-fold consts into LDS
    for (int i = tid; i < 3072; i += 512) wfS[i] = ws[WS_WFN + i];
    // z-dot vector
    if (tid < 256){
      vS[2*tid]   = Wpred[2*(NHID + CNND + tid)];
      vS[2*tid+1] = Wpred[2*(NHID + CNND + tid) + 1];
    }
    // H init (buffer 0)
    for (int i = tid; i < 4096; i += 512){
      const int a = i >> 8, e = i & 255;
      ((__hip_bfloat16*)Hl)[a*264 + e] = __float2bfloat16(nh0[e]);
    }
    float C[4][2];
    #pragma unroll
    for (int r = 0; r < 4; ++r)
      #pragma unroll
      for (int t = 0; t < 2; ++t)
        C[r][t] = nc0[jcol + t*16];

    __syncthreads();

    int cur = 0;
    for (int st = 1; st <= 78; ++st){
      const int thr  = (st <= 49) ? (50 - st) : -1;
      const int tsel = (st <= 49) ? st : 49;
      const short* hc = Hl + cur*HLH + llo*264 + lhi*8;

      f32x4 acc[4][2];
      #pragma unroll
      for (int g = 0; g < 4; ++g)
        #pragma unroll
        for (int t = 0; t < 2; ++t) acc[g][t] = (f32x4){0.f,0.f,0.f,0.f};

      // k[0,128): wreg
      #pragma unroll
      for (int ks = 0; ks < 4; ++ks){
        const bf16x8 af = *(const bf16x8*)(hc + ks*32);
        #pragma unroll
        for (int g = 0; g < 4; ++g)
          #pragma unroll
          for (int t = 0; t < 2; ++t)
            acc[g][t] = __builtin_amdgcn_mfma_f32_16x16x32_bf16(af, wreg[g][t][ks], acc[g][t], 0,0,0);
      }
      // k[128,192): LDS
      #pragma unroll
      for (int i = 0; i < 2; ++i){
        const bf16x8 af = *(const bf16x8*)(hc + (4+i)*32);
        #pragma unroll
        for (int g = 0; g < 4; ++g)
          #pragma unroll
          for (int t = 0; t < 2; ++t){
            const bf16x8 bw = *(const bf16x8*)(wlds + i*32768 + (g*256 + jcol + t*16)*32 + lhi*8);
            acc[g][t] = __builtin_amdgcn_mfma_f32_16x16x32_bf16(af, bw, acc[g][t], 0,0,0);
          }
      }
      // k[192,256): s67
      #pragma unroll
      for (int i = 0; i < 2; ++i){
        const bf16x8 af = *(const bf16x8*)(hc + (6+i)*32);
        #pragma unroll
        for (int g = 0; g < 4; ++g)
          #pragma unroll
          for (int t = 0; t < 2; ++t)
            acc[g][t] = __builtin_amdgcn_mfma_f32_16x16x32_bf16(af, s67[g][t][i], acc[g][t], 0,0,0);
      }

      // gates + masked update -> other H buffer
      {
        float2 rr[4]; bool mk[4];
        #pragma unroll
        for (int r = 0; r < 4; ++r){
          const int ag = n0 + lhi*4 + r;
          rr[r] = *(const float2*)(nrel + ag*100 + 2*tsel);
          mk[r] = nhist[ag] > thr;
        }
        volatile float* wfv = wfS;
        short* hn = Hl + (cur^1)*HLH;
        const short* ho = Hl + cur*HLH;
        #pragma unroll
        for (int t = 0; t < 2; ++t){
          const int j0 = jcol + t*16;
          float wfa[4], wfb[4], wbb[4];
          #pragma unroll
          for (int g = 0; g < 4; ++g){
            wfa[g] = wfv[g*256 + j0];
            wfb[g] = wfv[1024 + g*256 + j0];
            wbb[g] = wfv[2048 + g*256 + j0];
          }
          #pragma unroll
          for (int r = 0; r < 4; ++r){
            const int ag = lhi*4 + r;
            const float gi = acc[0][t][r] + rr[r].x*wfa[0] + rr[r].y*wfb[0] + wbb[0];
            const float gf = acc[1][t][r] + rr[r].x*wfa[1] + rr[r].y*wfb[1] + wbb[1];
            const float gg = acc[2][t][r] + rr[r].x*wfa[2] + rr[r].y*wfb[2] + wbb[2];
            const float go = acc[3][t][r] + rr[r].x*wfa[3] + rr[r].y*wfb[3] + wbb[3];
            const float c2 = sigf(gf)*C[r][t] + sigf(gi)*tanhfast(gg);
            const float h2 = sigf(go)*tanhfast(c2);
            const short hold = ho[ag*264 + j0];
            short hnew; { __hip_bfloat16 hb = __float2bfloat16(h2); hnew = *(short*)&hb; }
            if (mk[r]) C[r][t] = c2;
            hn[ag*264 + j0] = mk[r] ? hnew : hold;
          }
        }
      }
      __syncthreads();     // H[nxt] visible block-wide
      cur ^= 1;

      if (st >= 49){
        const int s = st - 49;
        const int a = wv*2 + (lane >> 5);
        const int sub = lane & 31;
        const short* hp = Hl + cur*HLH + a*264 + sub*8;
        volatile float* vv = vS;
        float z0 = 0.f, z1 = 0.f;
        #pragma unroll
        for (int i = 0; i < 8; ++i){
          const float h = bfs(hp[i]);
          z0 += h*vv[2*(sub*8 + i)];
          z1 += h*vv[2*(sub*8 + i) + 1];
        }
        #pragma unroll
        for (int o = 16; o > 0; o >>= 1){
          z0 += __shfl_down(z0, o, 32);
          z1 += __shfl_down(z1, o, 32);
        }
        if (sub == 0){
          ws[WS_Z + (s*NAG + n0 + a)*2]     = z0;
          ws[WS_Z + (s*NAG + n0 + a)*2 + 1] = z1;
        }
      }
    }
  }
  else if (b == 128){
    float* hT = (float*)smem;
    float* cT = hT + 128;
    float* gT = cT + 128;
    if (tid < 128){ hT[tid] = th0[tid]; cT[tid] = tc0[tid]; }
    __syncthreads();
    const int ths = thsp[0];
    for (int t = 1; t < 50; ++t){
      const float x0 = trel[2*t], x1 = trel[2*t+1];
      float acc = x0*ws[WS_WFT + tid] + x1*ws[WS_WFT + 512 + tid] + ws[WS_BFT + tid];
      for (int k = 0; k < 128; ++k) acc += hT[k]*Whht[k*512 + tid];
      gT[tid] = acc;
      __syncthreads();
      if (tid < 128 && ths > 50 - t){
        const float ig = sigf(gT[tid]),          fg = sigf(gT[128 + tid]);
        const float gg = tanhfast(gT[256 + tid]), og = sigf(gT[384 + tid]);
        const float c2 = fg*cT[tid] + ig*gg;
        cT[tid] = c2; hT[tid] = og*tanhfast(c2);
      }
      __syncthreads();
    }
    if (tid < 128){ ws[WS_TH + tid] = hT[tid]; ws[WS_TC + tid] = cT[tid]; }
  }
  else {
    float* at  = (float*)smem;        // 64
    float* red = at + 64;             // 512
    float* uv  = red + 512;           // 3
    const int t = LH - 1;
    const float tr0 = trel[2*t], tr1 = trel[2*t+1];
    const float tp0 = tpos[2*t], tp1 = tpos[2*t+1];
    if (tid < ADIM) at[tid] = tr0*Wtatt[tid] + tr1*Wtatt[ADIM+tid] + btatt[tid];
    int cnt = 0;
    #pragma unroll
    for (int i = 0; i < 4; ++i) cnt += (nhist[tid + 512*i] > (LH - t)) ? 1 : 0;
    red[tid] = (float)cnt;
    __syncthreads();
    if (tid == 0){
      float u0=0.f,u1=0.f,v=0.f;
      for (int k=0;k<ADIM;k++){ u0 += Wnatt[k]*at[k]; u1 += Wnatt[ADIM+k]*at[k]; v += bnatt[k]*at[k]; }
      uv[0]=u0; uv[1]=u1; uv[2]=v;
    }
    for (int s = 256; s > 0; s >>= 1){ if (tid < s) red[tid] += red[tid+s]; __syncthreads(); }
    const float currN = red[0];
    __syncthreads();
    const float u0 = uv[0], u1 = uv[1], v = uv[2];
    const float scale = currN * 0.125f;
    float sc[4]; float smax = -3.0e38f;
    #pragma unroll
    for (int i = 0; i < 4; ++i){
      const int n = tid + 512*i;
      const float p0 = npos[n*100 + 2*t], p1 = npos[n*100 + 2*t + 1];
      float s = scale * ((tp0-p0)*u0 + (tp1-p1)*u1 + v);
      s = (nhist[n] > (LH - t)) ? s : -1.0e30f;
      sc[i] = s; smax = fmaxf(smax, s);
    }
    red[tid] = smax; __syncthreads();
    for (int s = 256; s > 0; s >>= 1){ if (tid<s) red[tid] = fmaxf(red[tid], red[tid+s]); __syncthreads(); }
    smax = red[0]; __syncthreads();
    float ssum = 0.f;
    #pragma unroll
    for (int i = 0; i < 4; ++i){ sc[i] = __expf(sc[i]-smax); ssum += sc[i]; }
    red[tid] = ssum; __syncthreads();
    for (int s = 256; s > 0; s >>= 1){ if (tid<s) red[tid] += red[tid+s]; __syncthreads(); }
    const float inv = 1.0f / red[0];
    #pragma unroll
    for (int i = 0; i < 4; ++i) ws[WS_W49 + tid + 512*i] = sc[i]*inv;
    if (tid == 0) ws[WS_CN] = currN;
  }
}

// ---- Phase B: all 30 pred steps in one block ---------------------------------
template<int K>
__device__ __forceinline__ void bredN(const float* v, volatile float* scratch,
                                      volatile float* outv, int tid){
  const int lane = tid & 63, wv = tid >> 6;
  #pragma unroll
  for (int k = 0; k < K; ++k){
    float x = v[k];
    #pragma unroll
    for (int o = 32; o > 0; o >>= 1) x += __shfl_down(x, o, 64);
    if (lane == 0) scratch[k*8 + wv] = x;
  }
  __syncthreads();
  if (tid == 0){
    #pragma unroll
    for (int k = 0; k < K; ++k){
      float s = 0.f;
      for (int i = 0; i < 8; ++i) s += scratch[k*8 + i];
      outv[k] = s;
    }
  }
  __syncthreads();
}

__device__ __forceinline__ float bredMax1(float x, volatile float* scratch,
                                          volatile float* outv, int tid){
  const int lane = tid & 63, wv = tid >> 6;
  #pragma unroll
  for (int o = 32; o > 0; o >>= 1) x = fmaxf(x, __shfl_down(x, o, 64));
  if (lane == 0) scratch[wv] = x;
  __syncthreads();
  if (tid == 0){
    float s = -3.0e38f;
    for (int i = 0; i < 8; ++i) s = fmaxf(s, scratch[i]);
    outv[0] = s;
  }
  __syncthreads();
  return outv[0];
}

__global__ __launch_bounds__(512, 1) void k_phaseB(
    const float* __restrict__ img, const float* __restrict__ tpos,
    const float* __restrict__ npos, const float* __restrict__ nh0,
    const float* __restrict__ Wpred, const float* __restrict__ bpred,
    const float* __restrict__ Wtatt, const float* __restrict__ btatt,
    const float* __restrict__ Wnatt, const float* __restrict__ bnatt,
    float* __restrict__ ws, float* __restrict__ out)
{
  __shared__ float p0s[NAG], p1s[NAG];
  __shared__ float th[128], tc[128], gl[512], at[64];
  __shared__ float scratch[24];
  __shared__ float bc[8];
  const int tid = threadIdx.x, lane = tid & 63, wv = tid >> 6;

  bf16x8 wreg[16];
  {
    const short* wp = (const short*)(ws + WS_WHT) + tid*128;
    #pragma unroll
    for (int f = 0; f < 16; ++f) wreg[f] = *(const bf16x8*)(wp + f*8);
  }
  for (int n = tid; n < NAG; n += 512){
    p0s[n] = npos[n*100 + 98];
    p1s[n] = npos[n*100 + 99];
  }
  if (tid < 128){ th[tid] = ws[WS_TH + tid]; tc[tid] = ws[WS_TC + tid]; }

  {
    float v[2] = {0.f, 0.f};
    for (int k = tid; k < CNND; k += 512){
      v[0] += img[k]*Wpred[2*(128 + k)];
      v[1] += img[k]*Wpred[2*(128 + k) + 1];
    }
    bredN<2>(v, scratch, bc, tid);
  }
  const float imgW0 = bc[0], imgW1 = bc[1];
  {
    float v[2] = {0.f, 0.f};
    if (tid < 256){
      v[0] = nh0[tid]*Wpred[2*(128 + CNND + tid)];
      v[1] = nh0[tid]*Wpred[2*(128 + CNND + tid) + 1];
    }
    bredN<2>(v, scratch, bc + 2, tid);
  }
  const float fb0 = bc[2], fb1 = bc[3];
  const float currN = ws[WS_CN];
  float pos0 = tpos[98], pos1 = tpos[99];
  float u0 = 0.f, u1 = 0.f, A = 0.f;
  __syncthreads();

  for (int s = 0; s < PP; ++s){
    const float* zs = ws + WS_Z + s*(NAG*2);
    float hv0, hv1;
    if (s == 0){
      if (currN >= 1.0f){
        float v[2] = {0.f, 0.f};
        for (int n = tid; n < NAG; n += 512){
          const float w = ws[WS_W49 + n];
          v[0] += w*zs[2*n]; v[1] += w*zs[2*n + 1];
        }
        bredN<2>(v, scratch, bc, tid);
        hv0 = bc[0]; hv1 = bc[1];
      } else { hv0 = fb0; hv1 = fb1; }
    } else {
      float sc[4], mx = -3.0e38f;
      #pragma unroll
      for (int i = 0; i < 4; ++i){
        const int n = tid + 512*i;
        sc[i] = 256.0f * (A - (p0s[n]*u0 + p1s[n]*u1));
        mx = fmaxf(mx, sc[i]);
      }
      mx = bredMax1(mx, scratch, bc + 7, tid);
      float v[3] = {0.f, 0.f, 0.f};
      #pragma unroll
      for (int i = 0; i < 4; ++i){
        const int n = tid + 512*i;
        const float e = __expf(sc[i] - mx);
        v[0] += e; v[1] += e*zs[2*n]; v[2] += e*zs[2*n + 1];
      }
      bredN<3>(v, scratch, bc, tid);
      const float inv = 1.0f / bc[0];
      hv0 = bc[1]*inv; hv1 = bc[2]*inv;
    }
    {
      float v[2] = {0.f, 0.f};
      if (tid < 128){
        v[0] = th[tid]*Wpred[2*tid];
        v[1] = th[tid]*Wpred[2*tid + 1];
      }
      bredN<2>(v, scratch, bc + 2, tid);
    }
    const float pr0 = bc[2] + imgW0 + hv0 + bpred[0];
    const float pr1 = bc[3] + imgW1 + hv1 + bpred[1];
    if (tid == 0){ out[2*s] = pr0; out[2*s + 1] = pr1; }
    pos0 += pr0; pos1 += pr1;

    {
      float g = pr0*ws[WS_WFT + tid] + pr1*ws[WS_WFT + 512 + tid] + ws[WS_BFT + tid];
      #pragma unroll
      for (int f = 0; f < 16; ++f){
        #pragma unroll
        for (int i = 0; i < 8; ++i)
          g += bfs(wreg[f][i]) * th[f*8 + i];
      }
      gl[tid] = g;
    }
    __syncthreads();
    float hnew = 0.f, cnew = 0.f;
    if (tid < 128){
      const float ig = sigf(gl[tid]),           fg = sigf(gl[128 + tid]);
      const float gg = tanhfast(gl[256 + tid]), og = sigf(gl[384 + tid]);
      cnew = fg*tc[tid] + ig*gg;
      hnew = og*tanhfast(cnew);
    }
    __syncthreads();
    if (tid < 128){ th[tid] = hnew; tc[tid] = cnew; }

    if (tid < ADIM) at[tid] = pr0*Wtatt[tid] + pr1*Wtatt[ADIM + tid] + btatt[tid];
    __syncthreads();
    if (wv == 0){
      float uu0 = Wnatt[lane]*at[lane];
      float uu1 = Wnatt[ADIM + lane]*at[lane];
      float vv  = bnatt[lane]*at[lane];
      #pragma unroll
      for (int o = 32; o > 0; o >>= 1){
        uu0 += __shfl_down(uu0, o, 64);
        uu1 += __shfl_down(uu1, o, 64);
        vv  += __shfl_down(vv,  o, 64);
      }
      if (lane == 0){
        bc[4] = uu0; bc[5] = uu1;
        bc[6] = pos0*uu0 + pos1*uu1 + vv;
      }
    }
    __syncthreads();
    u0 = bc[4]; u1 = bc[5]; A = bc[6];
  }
}

extern "C" void kernel_launch(void* const* d_in, const int* in_sizes, int n_in,
                              void* d_out, int out_size, void* d_ws, size_t ws_size,
                              hipStream_t stream) {
  const float* img   = (const float*)d_in[0];
  const float* tpos  = (const float*)d_in[1];
  const float* trel  = (const float*)d_in[2];
  const float* npos  = (const float*)d_in[3];
  const float* nrel  = (const float*)d_in[4];
  const int*   nhist = (const int*)d_in[5];
  const int*   ths   = (const int*)d_in[6];
  const float* th0   = (const float*)d_in[7];
  const float* tc0   = (const float*)d_in[8];
  const float* Wtemb = (const float*)d_in[9];
  const float* btemb = (const float*)d_in[10];
  const float* Wiht  = (const float*)d_in[11];
  const float* Whht  = (const float*)d_in[12];
  const float* biht  = (const float*)d_in[13];
  const float* bhht  = (const float*)d_in[14];
  const float* Wtatt = (const float*)d_in[15];
  const float* btatt = (const float*)d_in[16];
  const float* nh0   = (const float*)d_in[17];
  const float* nc0   = (const float*)d_in[18];
  const float* Wnemb = (const float*)d_in[19];
  const float* bnemb = (const float*)d_in[20];
  const float* Wihn  = (const float*)d_in[21];
  const float* Whhn  = (const float*)d_in[22];
  const float* bihn  = (const float*)d_in[23];
  const float* bhhn  = (const float*)d_in[24];
  const float* Wnatt = (const float*)d_in[25];
  const float* bnatt = (const float*)d_in[26];
  const float* Wpred = (const float*)d_in[27];
  const float* bpred = (const float*)d_in[28];
  float* ws  = (float*)d_ws;
  float* out = (float*)d_out;

  const int ldsA = 131072 + 16896 + 3072*4 + 512*4;   // 162304 B

  k_prep<<<257, 256, 0, stream>>>(Whhn, Whht, Wnemb, bnemb, Wihn, bihn, bhhn,
                                  Wtemb, btemb, Wiht, biht, bhht, ws);
  k_phaseA<<<130, 512, ldsA, stream>>>(nh0, nc0, nrel, nhist, Wpred,
                                       trel, ths, Whht, th0, tc0,
                                       tpos, npos, Wtatt, btatt, Wnatt, bnatt, ws);
  k_phaseB<<<1, 512, 0, stream>>>(img, tpos, npos, nh0, Wpred, bpred,
                                  Wtatt, btatt, Wnatt, bnatt, ws, out);
}

// Round 9
// 960.387 us; speedup vs baseline: 1.1631x; 1.0178x over previous
//
#include <hip/hip_runtime.h>
#include <hip/hip_bf16.h>
#include <cstdint>

#define LH   50
#define PP   30
#define NAG  2048
#define NHID 128
#define EHID 256
#define ADIM 64
#define CNND 2048

typedef __attribute__((ext_vector_type(8))) short bf16x8;
typedef __attribute__((ext_vector_type(4))) float f32x4;

// ---- workspace layout (float slots) -----------------------------------------
enum : int {
  WS_WT  = 0,        // bf16 chunks [8][1024][32] (k-chunked WhhT) -> 131072 fl (512KB)
  WS_WHT = 131072,   // bf16 WhtT[512][128] -> 32768
  WS_WFN = 163840,   // wf0[1024] wf1[1024] (folded W_nemb@Wih_n)
  WS_BFN = 165888,   // wb[1024]
  WS_WFT = 166912,   // 2*512 folded (W_temb@Wih_t)
  WS_BFT = 167936,   // 512
  WS_TH  = 168448,   // 128
  WS_TC  = 168576,   // 128
  WS_W49 = 168704,   // 2048
  WS_CN  = 170752,   // 1 (+3 pad)
  WS_Z   = 170756,   // 30*2048*2
  WS_END = 293636
};

#define HLH 4224   // shorts per Hl buffer (16 rows x 264)

__device__ __forceinline__ float sigf(float x){ return 1.0f/(1.0f + __expf(-x)); }
__device__ __forceinline__ float tanhfast(float x){
  x = fminf(15.0f, fmaxf(-15.0f, x));
  float e = __expf(2.0f*x);
  return (e - 1.0f)/(e + 1.0f);
}
__device__ __forceinline__ float bfs(short s){
  return __uint_as_float(((unsigned)(unsigned short)s) << 16);
}

// ---- prep: WhhT k-chunks [8][1024][32], WhtT, folded gate weights ------------
__global__ void k_prep(const float* __restrict__ Whhn, const float* __restrict__ Whht,
                       const float* __restrict__ Wnemb, const float* __restrict__ bnemb,
                       const float* __restrict__ Wihn,  const float* __restrict__ bihn,
                       const float* __restrict__ bhhn,
                       const float* __restrict__ Wtemb, const float* __restrict__ btemb,
                       const float* __restrict__ Wiht,  const float* __restrict__ biht,
                       const float* __restrict__ bhht,
                       float* __restrict__ ws)
{
  const int b = blockIdx.x, tid = threadIdx.x;
  if (b < 256){
    __shared__ float t[32][33];
    __hip_bfloat16* WT = (__hip_bfloat16*)(ws + WS_WT);
    const int tx = tid & 31, ty = tid >> 5;     // ty in [0,8)
    const int j0 = (b & 31) << 5;
    const int e0 = (b >> 5) << 5;               // k-range [0,256)
    #pragma unroll
    for (int r = 0; r < 4; ++r)
      t[ty + 8*r][tx] = Whhn[(e0 + ty + 8*r)*1024 + j0 + tx];
    __syncthreads();
    const int c = e0 >> 5;                      // 0..7
    #pragma unroll
    for (int r = 0; r < 4; ++r)
      WT[c*32768 + (j0 + ty + 8*r)*32 + tx] = __float2bfloat16(t[tx][ty + 8*r]);
  } else {
    for (int j = tid; j < 1024; j += 256){
      float a0=0.f, a1=0.f, ab=0.f;
      for (int k=0;k<64;k++){
        const float w = Wihn[k*1024 + j];
        a0 += Wnemb[k]*w; a1 += Wnemb[64+k]*w; ab += bnemb[k]*w;
      }
      ws[WS_WFN + j]        = a0;
      ws[WS_WFN + 1024 + j] = a1;
      ws[WS_BFN + j]        = ab + bihn[j] + bhhn[j];
    }
    for (int j = tid; j < 512; j += 256){
      float a0=0.f, a1=0.f, ab=0.f;
      for (int k=0;k<64;k++){
        const float w = Wiht[k*512 + j];
        a0 += Wtemb[k]*w; a1 += Wtemb[64+k]*w; ab += btemb[k]*w;
      }
      ws[WS_WFT + j]       = a0;
      ws[WS_WFT + 512 + j] = a1;
      ws[WS_BFT + j]       = ab + biht[j] + bhht[j];
    }
    __hip_bfloat16* WTt = (__hip_bfloat16*)(ws + WS_WHT);
    for (int j = tid; j < 512; j += 256)
      for (int k = 0; k < 128; ++k)
        WTt[j*128 + k] = __float2bfloat16(Whht[k*512 + j]);
  }
}

// ---- Phase A ------------------------------------------------------------------
// b<128: 16-agent 78-step nearby chain. FULL W on-CU:
//   k[0,128) in wreg (128 VGPR), k[128,192) in LDS (128KB, staged once),
//   k[192,256) in s67 (64 VGPR). Zero weight streaming in the loop.
//   H double-buffered in LDS -> ONE barrier per step.
// b==128: target obs chain.  b==129: w49 precompute.
// dynamic LDS: wlds 131072 | Hl 2x4224 shorts (16896) | wfS 3072 fl | vS 512 fl
__global__ __launch_bounds__(512, 1) void k_phaseA(
    const float* __restrict__ nh0, const float* __restrict__ nc0,
    const float* __restrict__ nrel, const int* __restrict__ nhist,
    const float* __restrict__ Wpred,
    const float* __restrict__ trel, const int* __restrict__ thsp,
    const float* __restrict__ Whht, const float* __restrict__ th0,
    const float* __restrict__ tc0,
    const float* __restrict__ tpos, const float* __restrict__ npos,
    const float* __restrict__ Wtatt, const float* __restrict__ btatt,
    const float* __restrict__ Wnatt, const float* __restrict__ bnatt,
    float* __restrict__ ws)
{
  extern __shared__ char smem[];
  const int b = blockIdx.x, tid = threadIdx.x;
  const int wv = tid >> 6, lane = tid & 63;
  const int lhi = lane >> 4, llo = lane & 15;

  if (b < 128){
    short* wlds = (short*)smem;                   // [2][1024][32] shorts (131072 B)
    short* Hl   = (short*)(smem + 131072);        // 2 x 4224 shorts
    float* wfS  = (float*)(smem + 147968);        // 3072 floats
    float* vS   = (float*)(smem + 160256);        // 512 floats
    const int n0 = b << 4;
    const int jcol = (wv << 5) + llo;
    const short* wt = (const short*)(ws + WS_WT);

    // register-resident W: k[0,128) and k[192,256)
    bf16x8 wreg[4][2][4];
    bf16x8 s67[4][2][2];
    #pragma unroll
    for (int g = 0; g < 4; ++g)
      #pragma unroll
      for (int t = 0; t < 2; ++t){
        const int j = g*256 + jcol + t*16;
        #pragma unroll
        for (int ks = 0; ks < 4; ++ks)
          wreg[g][t][ks] = *(const bf16x8*)(wt + ks*32768 + j*32 + lhi*8);
        #pragma unroll
        for (int i = 0; i < 2; ++i)
          s67[g][t][i] = *(const bf16x8*)(wt + (6+i)*32768 + j*32 + lhi*8);
      }
    // LDS-resident W: chunks 4,5 (linear copy, staged once)
    for (int i = tid; i < 8192; i += 512)
      *(uint4*)(wlds + i*8) = *(const uint4*)(wt + 4*32768 + i*8);
    // gate-fold consts into LDS
    for (int i = tid; i < 3072; i += 512) wfS[i] = ws[WS_WFN + i];
    // z-dot vector
    if (tid < 256){
      vS[2*tid]   = Wpred[2*(NHID + CNND + tid)];
      vS[2*tid+1] = Wpred[2*(NHID + CNND + tid) + 1];
    }
    // H init (buffer 0)
    for (int i = tid; i < 4096; i += 512){
      const int a = i >> 8, e = i & 255;
      ((__hip_bfloat16*)Hl)[a*264 + e] = __float2bfloat16(nh0[e]);
    }
    float C[4][2];
    #pragma unroll
    for (int r = 0; r < 4; ++r)
      #pragma unroll
      for (int t = 0; t < 2; ++t)
        C[r][t] = nc0[jcol + t*16];

    __syncthreads();

    int cur = 0;
    for (int st = 1; st <= 78; ++st){
      const int thr  = (st <= 49) ? (50 - st) : -1;
      const int tsel = (st <= 49) ? st : 49;
      const short* hc = Hl + cur*HLH + llo*264 + lhi*8;

      f32x4 acc[4][2];
      #pragma unroll
      for (int g = 0; g < 4; ++g)
        #pragma unroll
        for (int t = 0; t < 2; ++t) acc[g][t] = (f32x4){0.f,0.f,0.f,0.f};

      // k[0,128): wreg
      #pragma unroll
      for (int ks = 0; ks < 4; ++ks){
        const bf16x8 af = *(const bf16x8*)(hc + ks*32);
        #pragma unroll
        for (int g = 0; g < 4; ++g)
          #pragma unroll
          for (int t = 0; t < 2; ++t)
            acc[g][t] = __builtin_amdgcn_mfma_f32_16x16x32_bf16(af, wreg[g][t][ks], acc[g][t], 0,0,0);
      }
      // k[128,192): LDS
      #pragma unroll
      for (int i = 0; i < 2; ++i){
        const bf16x8 af = *(const bf16x8*)(hc + (4+i)*32);
        #pragma unroll
        for (int g = 0; g < 4; ++g)
          #pragma unroll
          for (int t = 0; t < 2; ++t){
            const bf16x8 bw = *(const bf16x8*)(wlds + i*32768 + (g*256 + jcol + t*16)*32 + lhi*8);
            acc[g][t] = __builtin_amdgcn_mfma_f32_16x16x32_bf16(af, bw, acc[g][t], 0,0,0);
          }
      }
      // k[192,256): s67
      #pragma unroll
      for (int i = 0; i < 2; ++i){
        const bf16x8 af = *(const bf16x8*)(hc + (6+i)*32);
        #pragma unroll
        for (int g = 0; g < 4; ++g)
          #pragma unroll
          for (int t = 0; t < 2; ++t)
            acc[g][t] = __builtin_amdgcn_mfma_f32_16x16x32_bf16(af, s67[g][t][i], acc[g][t], 0,0,0);
      }

      // gates + masked update -> other H buffer
      {
        float2 rr[4]; bool mk[4];
        #pragma unroll
        for (int r = 0; r < 4; ++r){
          const int ag = n0 + lhi*4 + r;
          rr[r] = *(const float2*)(nrel + ag*100 + 2*tsel);
          mk[r] = nhist[ag] > thr;
        }
        volatile float* wfv = wfS;
        short* hn = Hl + (cur^1)*HLH;
        const short* ho = Hl + cur*HLH;
        #pragma unroll
        for (int t = 0; t < 2; ++t){
          const int j0 = jcol + t*16;
          float wfa[4], wfb[4], wbb[4];
          #pragma unroll
          for (int g = 0; g < 4; ++g){
            wfa[g] = wfv[g*256 + j0];
            wfb[g] = wfv[1024 + g*256 + j0];
            wbb[g] = wfv[2048 + g*256 + j0];
          }
          #pragma unroll
          for (int r = 0; r < 4; ++r){
            const int ag = lhi*4 + r;
            const float gi = acc[0][t][r] + rr[r].x*wfa[0] + rr[r].y*wfb[0] + wbb[0];
            const float gf = acc[1][t][r] + rr[r].x*wfa[1] + rr[r].y*wfb[1] + wbb[1];
            const float gg = acc[2][t][r] + rr[r].x*wfa[2] + rr[r].y*wfb[2] + wbb[2];
            const float go = acc[3][t][r] + rr[r].x*wfa[3] + rr[r].y*wfb[3] + wbb[3];
            const float c2 = sigf(gf)*C[r][t] + sigf(gi)*tanhfast(gg);
            const float h2 = sigf(go)*tanhfast(c2);
            const short hold = ho[ag*264 + j0];
            short hnew; { __hip_bfloat16 hb = __float2bfloat16(h2); hnew = *(short*)&hb; }
            if (mk[r]) C[r][t] = c2;
            hn[ag*264 + j0] = mk[r] ? hnew : hold;
          }
        }
      }
      __syncthreads();     // H[nxt] visible block-wide
      cur ^= 1;

      if (st >= 49){
        const int s = st - 49;
        const int a = wv*2 + (lane >> 5);
        const int sub = lane & 31;
        const short* hp = Hl + cur*HLH + a*264 + sub*8;
        volatile float* vv = vS;
        float z0 = 0.f, z1 = 0.f;
        #pragma unroll
        for (int i = 0; i < 8; ++i){
          const float h = bfs(hp[i]);
          z0 += h*vv[2*(sub*8 + i)];
          z1 += h*vv[2*(sub*8 + i) + 1];
        }
        #pragma unroll
        for (int o = 16; o > 0; o >>= 1){
          z0 += __shfl_down(z0, o, 32);
          z1 += __shfl_down(z1, o, 32);
        }
        if (sub == 0){
          ws[WS_Z + (s*NAG + n0 + a)*2]     = z0;
          ws[WS_Z + (s*NAG + n0 + a)*2 + 1] = z1;
        }
      }
    }
  }
  else if (b == 128){
    float* hT = (float*)smem;
    float* cT = hT + 128;
    float* gT = cT + 128;
    if (tid < 128){ hT[tid] = th0[tid]; cT[tid] = tc0[tid]; }
    __syncthreads();
    const int ths = thsp[0];
    for (int t = 1; t < 50; ++t){
      const float x0 = trel[2*t], x1 = trel[2*t+1];
      float acc = x0*ws[WS_WFT + tid] + x1*ws[WS_WFT + 512 + tid] + ws[WS_BFT + tid];
      for (int k = 0; k < 128; ++k) acc += hT[k]*Whht[k*512 + tid];
      gT[tid] = acc;
      __syncthreads();
      if (tid < 128 && ths > 50 - t){
        const float ig = sigf(gT[tid]),          fg = sigf(gT[128 + tid]);
        const float gg = tanhfast(gT[256 + tid]), og = sigf(gT[384 + tid]);
        const float c2 = fg*cT[tid] + ig*gg;
        cT[tid] = c2; hT[tid] = og*tanhfast(c2);
      }
      __syncthreads();
    }
    if (tid < 128){ ws[WS_TH + tid] = hT[tid]; ws[WS_TC + tid] = cT[tid]; }
  }
  else {
    float* at  = (float*)smem;        // 64
    float* red = at + 64;             // 512
    float* uv  = red + 512;           // 3
    const int t = LH - 1;
    const float tr0 = trel[2*t], tr1 = trel[2*t+1];
    const float tp0 = tpos[2*t], tp1 = tpos[2*t+1];
    if (tid < ADIM) at[tid] = tr0*Wtatt[tid] + tr1*Wtatt[ADIM+tid] + btatt[tid];
    int cnt = 0;
    #pragma unroll
    for (int i = 0; i < 4; ++i) cnt += (nhist[tid + 512*i] > (LH - t)) ? 1 : 0;
    red[tid] = (float)cnt;
    __syncthreads();
    if (tid == 0){
      float u0=0.f,u1=0.f,v=0.f;
      for (int k=0;k<ADIM;k++){ u0 += Wnatt[k]*at[k]; u1 += Wnatt[ADIM+k]*at[k]; v += bnatt[k]*at[k]; }
      uv[0]=u0; uv[1]=u1; uv[2]=v;
    }
    for (int s = 256; s > 0; s >>= 1){ if (tid < s) red[tid] += red[tid+s]; __syncthreads(); }
    const float currN = red[0];
    __syncthreads();
    const float u0 = uv[0], u1 = uv[1], v = uv[2];
    const float scale = currN * 0.125f;
    float sc[4]; float smax = -3.0e38f;
    #pragma unroll
    for (int i = 0; i < 4; ++i){
      const int n = tid + 512*i;
      const float p0 = npos[n*100 + 2*t], p1 = npos[n*100 + 2*t + 1];
      float s = scale * ((tp0-p0)*u0 + (tp1-p1)*u1 + v);
      s = (nhist[n] > (LH - t)) ? s : -1.0e30f;
      sc[i] = s; smax = fmaxf(smax, s);
    }
    red[tid] = smax; __syncthreads();
    for (int s = 256; s > 0; s >>= 1){ if (tid<s) red[tid] = fmaxf(red[tid], red[tid+s]); __syncthreads(); }
    smax = red[0]; __syncthreads();
    float ssum = 0.f;
    #pragma unroll
    for (int i = 0; i < 4; ++i){ sc[i] = __expf(sc[i]-smax); ssum += sc[i]; }
    red[tid] = ssum; __syncthreads();
    for (int s = 256; s > 0; s >>= 1){ if (tid<s) red[tid] += red[tid+s]; __syncthreads(); }
    const float inv = 1.0f / red[0];
    #pragma unroll
    for (int i = 0; i < 4; ++i) ws[WS_W49 + tid + 512*i] = sc[i]*inv;
    if (tid == 0) ws[WS_CN] = currN;
  }
}

// ---- Phase B: all 30 pred steps in one block ---------------------------------
template<int K>
__device__ __forceinline__ void bredN(const float* v, volatile float* scratch,
                                      volatile float* outv, int tid){
  const int lane = tid & 63, wv = tid >> 6;
  #pragma unroll
  for (int k = 0; k < K; ++k){
    float x = v[k];
    #pragma unroll
    for (int o = 32; o > 0; o >>= 1) x += __shfl_down(x, o, 64);
    if (lane == 0) scratch[k*8 + wv] = x;
  }
  __syncthreads();
  if (tid == 0){
    #pragma unroll
    for (int k = 0; k < K; ++k){
      float s = 0.f;
      for (int i = 0; i < 8; ++i) s += scratch[k*8 + i];
      outv[k] = s;
    }
  }
  __syncthreads();
}

__device__ __forceinline__ float bredMax1(float x, volatile float* scratch,
                                          volatile float* outv, int tid){
  const int lane = tid & 63, wv = tid >> 6;
  #pragma unroll
  for (int o = 32; o > 0; o >>= 1) x = fmaxf(x, __shfl_down(x, o, 64));
  if (lane == 0) scratch[wv] = x;
  __syncthreads();
  if (tid == 0){
    float s = -3.0e38f;
    for (int i = 0; i < 8; ++i) s = fmaxf(s, scratch[i]);
    outv[0] = s;
  }
  __syncthreads();
  return outv[0];
}

__global__ __launch_bounds__(512, 1) void k_phaseB(
    const float* __restrict__ img, const float* __restrict__ tpos,
    const float* __restrict__ npos, const float* __restrict__ nh0,
    const float* __restrict__ Wpred, const float* __restrict__ bpred,
    const float* __restrict__ Wtatt, const float* __restrict__ btatt,
    const float* __restrict__ Wnatt, const float* __restrict__ bnatt,
    float* __restrict__ ws, float* __restrict__ out)
{
  __shared__ float p0s[NAG], p1s[NAG];
  __shared__ float th[128], tc[128], gl[512], at[64];
  __shared__ float scratch[24];
  __shared__ float bc[8];
  const int tid = threadIdx.x, lane = tid & 63, wv = tid >> 6;

  bf16x8 wreg[16];
  {
    const short* wp = (const short*)(ws + WS_WHT) + tid*128;
    #pragma unroll
    for (int f = 0; f < 16; ++f) wreg[f] = *(const bf16x8*)(wp + f*8);
  }
  for (int n = tid; n < NAG; n += 512){
    p0s[n] = npos[n*100 + 98];
    p1s[n] = npos[n*100 + 99];
  }
  if (tid < 128){ th[tid] = ws[WS_TH + tid]; tc[tid] = ws[WS_TC + tid]; }

  {
    float v[2] = {0.f, 0.f};
    for (int k = tid; k < CNND; k += 512){
      v[0] += img[k]*Wpred[2*(128 + k)];
      v[1] += img[k]*Wpred[2*(128 + k) + 1];
    }
    bredN<2>(v, scratch, bc, tid);
  }
  const float imgW0 = bc[0], imgW1 = bc[1];
  {
    float v[2] = {0.f, 0.f};
    if (tid < 256){
      v[0] = nh0[tid]*Wpred[2*(128 + CNND + tid)];
      v[1] = nh0[tid]*Wpred[2*(128 + CNND + tid) + 1];
    }
    bredN<2>(v, scratch, bc + 2, tid);
  }
  const float fb0 = bc[2], fb1 = bc[3];
  const float currN = ws[WS_CN];
  float pos0 = tpos[98], pos1 = tpos[99];
  float u0 = 0.f, u1 = 0.f, A = 0.f;
  __syncthreads();

  for (int s = 0; s < PP; ++s){
    const float* zs = ws + WS_Z + s*(NAG*2);
    float hv0, hv1;
    if (s == 0){
      if (currN >= 1.0f){
        float v[2] = {0.f, 0.f};
        for (int n = tid; n < NAG; n += 512){
          const float w = ws[WS_W49 + n];
          v[0] += w*zs[2*n]; v[1] += w*zs[2*n + 1];
        }
        bredN<2>(v, scratch, bc, tid);
        hv0 = bc[0]; hv1 = bc[1];
      } else { hv0 = fb0; hv1 = fb1; }
    } else {
      float sc[4], mx = -3.0e38f;
      #pragma unroll
      for (int i = 0; i < 4; ++i){
        const int n = tid + 512*i;
        sc[i] = 256.0f * (A - (p0s[n]*u0 + p1s[n]*u1));
        mx = fmaxf(mx, sc[i]);
      }
      mx = bredMax1(mx, scratch, bc + 7, tid);
      float v[3] = {0.f, 0.f, 0.f};
      #pragma unroll
      for (int i = 0; i < 4; ++i){
        const int n = tid + 512*i;
        const float e = __expf(sc[i] - mx);
        v[0] += e; v[1] += e*zs[2*n]; v[2] += e*zs[2*n + 1];
      }
      bredN<3>(v, scratch, bc, tid);
      const float inv = 1.0f / bc[0];
      hv0 = bc[1]*inv; hv1 = bc[2]*inv;
    }
    {
      float v[2] = {0.f, 0.f};
      if (tid < 128){
        v[0] = th[tid]*Wpred[2*tid];
        v[1] = th[tid]*Wpred[2*tid + 1];
      }
      bredN<2>(v, scratch, bc + 2, tid);
    }
    const float pr0 = bc[2] + imgW0 + hv0 + bpred[0];
    const float pr1 = bc[3] + imgW1 + hv1 + bpred[1];
    if (tid == 0){ out[2*s] = pr0; out[2*s + 1] = pr1; }
    pos0 += pr0; pos1 += pr1;

    {
      float g = pr0*ws[WS_WFT + tid] + pr1*ws[WS_WFT + 512 + tid] + ws[WS_BFT + tid];
      #pragma unroll
      for (int f = 0; f < 16; ++f){
        #pragma unroll
        for (int i = 0; i < 8; ++i)
          g += bfs(wreg[f][i]) * th[f*8 + i];
      }
      gl[tid] = g;
    }
    __syncthreads();
    float hnew = 0.f, cnew = 0.f;
    if (tid < 128){
      const float ig = sigf(gl[tid]),           fg = sigf(gl[128 + tid]);
      const float gg = tanhfast(gl[256 + tid]), og = sigf(gl[384 + tid]);
      cnew = fg*tc[tid] + ig*gg;
      hnew = og*tanhfast(cnew);
    }
    __syncthreads();
    if (tid < 128){ th[tid] = hnew; tc[tid] = cnew; }

    if (tid < ADIM) at[tid] = pr0*Wtatt[tid] + pr1*Wtatt[ADIM + tid] + btatt[tid];
    __syncthreads();
    if (wv == 0){
      float uu0 = Wnatt[lane]*at[lane];
      float uu1 = Wnatt[ADIM + lane]*at[lane];
      float vv  = bnatt[lane]*at[lane];
      #pragma unroll
      for (int o = 32; o > 0; o >>= 1){
        uu0 += __shfl_down(uu0, o, 64);
        uu1 += __shfl_down(uu1, o, 64);
        vv  += __shfl_down(vv,  o, 64);
      }
      if (lane == 0){
        bc[4] = uu0; bc[5] = uu1;
        bc[6] = pos0*uu0 + pos1*uu1 + vv;
      }
    }
    __syncthreads();
    u0 = bc[4]; u1 = bc[5]; A = bc[6];
  }
}

extern "C" void kernel_launch(void* const* d_in, const int* in_sizes, int n_in,
                              void* d_out, int out_size, void* d_ws, size_t ws_size,
                              hipStream_t stream) {
  const float* img   = (const float*)d_in[0];
  const float* tpos  = (const float*)d_in[1];
  const float* trel  = (const float*)d_in[2];
  const float* npos  = (const float*)d_in[3];
  const float* nrel  = (const float*)d_in[4];
  const int*   nhist = (const int*)d_in[5];
  const int*   ths   = (const int*)d_in[6];
  const float* th0   = (const float*)d_in[7];
  const float* tc0   = (const float*)d_in[8];
  const float* Wtemb = (const float*)d_in[9];
  const float* btemb = (const float*)d_in[10];
  const float* Wiht  = (const float*)d_in[11];
  const float* Whht  = (const float*)d_in[12];
  const float* biht  = (const float*)d_in[13];
  const float* bhht  = (const float*)d_in[14];
  const float* Wtatt = (const float*)d_in[15];
  const float* btatt = (const float*)d_in[16];
  const float* nh0   = (const float*)d_in[17];
  const float* nc0   = (const float*)d_in[18];
  const float* Wnemb = (const float*)d_in[19];
  const float* bnemb = (const float*)d_in[20];
  const float* Wihn  = (const float*)d_in[21];
  const float* Whhn  = (const float*)d_in[22];
  const float* bihn  = (const float*)d_in[23];
  const float* bhhn  = (const float*)d_in[24];
  const float* Wnatt = (const float*)d_in[25];
  const float* bnatt = (const float*)d_in[26];
  const float* Wpred = (const float*)d_in[27];
  const float* bpred = (const float*)d_in[28];
  float* ws  = (float*)d_ws;
  float* out = (float*)d_out;

  const int ldsA = 131072 + 16896 + 3072*4 + 512*4;   // 162304 B

  k_prep<<<257, 256, 0, stream>>>(Whhn, Whht, Wnemb, bnemb, Wihn, bihn, bhhn,
                                  Wtemb, btemb, Wiht, biht, bhht, ws);
  k_phaseA<<<130, 512, ldsA, stream>>>(nh0, nc0, nrel, nhist, Wpred,
                                       trel, ths, Whht, th0, tc0,
                                       tpos, npos, Wtatt, btatt, Wnatt, bnatt, ws);
  k_phaseB<<<1, 512, 0, stream>>>(img, tpos, npos, nh0, Wpred, bpred,
                                  Wtatt, btatt, Wnatt, bnatt, ws, out);
}